// Round 17
// baseline (492.471 us; speedup 1.0000x reference)
//
#include <hip/hip_runtime.h>

// ---------------- problem constants ----------------
constexpr int NB  = 32;     // batch
constexpr int NS  = 1024;   // seq
constexpr int NH  = 768;    // hidden
constexpr int NH2 = 1536;   // 2*hidden
constexpr int NQKV = 2304;  // 3*hidden
constexpr int NBS = NB * NS;

typedef __bf16 bf16x8 __attribute__((ext_vector_type(8)));
typedef float  f32x4  __attribute__((ext_vector_type(4)));
typedef unsigned short u16x8 __attribute__((ext_vector_type(8)));
typedef _Float16 f16x8 __attribute__((ext_vector_type(8)));
typedef _Float16 f16x4 __attribute__((ext_vector_type(4)));

__device__ __forceinline__ unsigned short f2bf(float f) {
  unsigned int u = __builtin_bit_cast(unsigned int, f);
  u += 0x7FFFu + ((u >> 16) & 1u);
  return (unsigned short)(u >> 16);
}
__device__ __forceinline__ float bf2f(unsigned short h) {
  return __builtin_bit_cast(float, ((unsigned int)h) << 16);
}

#define GLDS16(g, l)                                                         \
  __builtin_amdgcn_global_load_lds(                                          \
      (__attribute__((address_space(1))) void*)(g),                          \
      (__attribute__((address_space(3))) void*)(l), 16, 0, 0)

#define SBAR()    asm volatile("s_barrier" ::: "memory")
#define WAITVM6() asm volatile("s_waitcnt vmcnt(6)" ::: "memory")
#define WAITVM4() asm volatile("s_waitcnt vmcnt(4)" ::: "memory")
#define WAITVM0() asm volatile("s_waitcnt vmcnt(0)" ::: "memory")
#define LGKM0()                                                              \
  do {                                                                       \
    asm volatile("s_waitcnt lgkmcnt(0)" ::: "memory");                       \
    __builtin_amdgcn_sched_barrier(0);                                       \
  } while (0)

// ---------------- cond stage 0: gather + transpose ----------------
__launch_bounds__(256)
__global__ void cond_pre(const int* __restrict__ relation,
                         const float* __restrict__ h,
                         const int* __restrict__ subh,
                         const int* __restrict__ subt,
                         const float* __restrict__ rel_emb,
                         float* __restrict__ reT, float* __restrict__ condT) {
  const int b = blockIdx.x, t = threadIdx.x;
  const int r = relation[b], sh = subh[b], st = subt[b];
  for (int k = t; k < NH; k += 256) {
    reT[(size_t)k * NB + b] = rel_emb[(size_t)r * NH + k];
    condT[(size_t)(NH + k) * NB + b] =
        0.5f * (h[((size_t)b * NS + sh) * NH + k] +
                h[((size_t)b * NS + st) * NH + k]);
  }
}

// ---------------- cond stage 1: rel_feature = relu6(re @ W_rf^T + b_rf) ----
__launch_bounds__(256)
__global__ void cond_rf(const float* __restrict__ W_rf,
                        const float* __restrict__ b_rf,
                        const float* __restrict__ reT,
                        float* __restrict__ condT) {
  const int t = threadIdx.x;
  const int b = t & 31, jl = t >> 5;
  const int j = blockIdx.x * 8 + jl;
  const float4* w4 = (const float4*)(W_rf + (size_t)j * NH);
  const float* rT = reT + b;
  float a0 = 0.f, a1 = 0.f;
  for (int k4 = 0; k4 < NH / 4; k4++) {
    float4 w = w4[k4];
    const float* c = rT + (size_t)(k4 * 4) * NB;
    a0 += w.x * c[0] + w.y * c[NB];
    a1 += w.z * c[2 * NB] + w.w * c[3 * NB];
  }
  float acc = a0 + a1 + b_rf[j];
  condT[(size_t)j * NB + b] = fminf(fmaxf(acc, 0.0f), 6.0f);
}

// ---------------- cond stage 2: wt/bs = cond @ W_{wd,bd}^T + gamma/beta ----
__launch_bounds__(256)
__global__ void cond_wb(const float* __restrict__ W_wd,
                        const float* __restrict__ W_bd,
                        const float* __restrict__ gamma,
                        const float* __restrict__ beta,
                        const float* __restrict__ condT,
                        float* __restrict__ wt, float* __restrict__ bs) {
  __shared__ float redW[128], redB[128];
  const int t = threadIdx.x;
  const int b = t & 31, jl = (t >> 5) & 3, ks = t >> 7;
  const int j = blockIdx.x * 4 + jl;
  const float4* ww = (const float4*)(W_wd + (size_t)j * NH2 + ks * NH);
  const float4* wb = (const float4*)(W_bd + (size_t)j * NH2 + ks * NH);
  const float* cT = condT + (size_t)ks * NH * NB + b;
  float aw0 = 0.f, aw1 = 0.f, ab0 = 0.f, ab1 = 0.f;
  for (int k4 = 0; k4 < NH / 4; k4++) {
    float4 w = ww[k4];
    float4 v = wb[k4];
    const float* c = cT + (size_t)(k4 * 4) * NB;
    float c0 = c[0], c1 = c[NB], c2 = c[2 * NB], c3 = c[3 * NB];
    aw0 += w.x * c0 + w.y * c1;
    aw1 += w.z * c2 + w.w * c3;
    ab0 += v.x * c0 + v.y * c1;
    ab1 += v.z * c2 + v.w * c3;
  }
  float aw = aw0 + aw1, ab = ab0 + ab1;
  if (ks == 1) {
    redW[t - 128] = aw;
    redB[t - 128] = ab;
  }
  __syncthreads();
  if (ks == 0) {
    aw += redW[t];
    ab += redB[t];
    wt[(size_t)b * NH + j] = aw + gamma[j];
    bs[(size_t)b * NH + j] = ab + beta[j];
  }
}

// ---------------- conditional layernorm -> x (bf16) ----------------
__launch_bounds__(64)
__global__ void ln_kernel(const float* __restrict__ h,
                          const float* __restrict__ wt,
                          const float* __restrict__ bs,
                          unsigned short* __restrict__ xbf) {
  const int row = blockIdx.x;      // 0..NBS-1
  const int b = row >> 10;
  const int lane = threadIdx.x;    // 0..63
  const float4* hr = (const float4*)(h + (size_t)row * NH);
  float4 v0 = hr[lane], v1 = hr[lane + 64], v2 = hr[lane + 128];
  float sum = 0.f, sq = 0.f;
  {
    sum += v0.x + v0.y + v0.z + v0.w;
    sq  += v0.x * v0.x + v0.y * v0.y + v0.z * v0.z + v0.w * v0.w;
    sum += v1.x + v1.y + v1.z + v1.w;
    sq  += v1.x * v1.x + v1.y * v1.y + v1.z * v1.z + v1.w * v1.w;
    sum += v2.x + v2.y + v2.z + v2.w;
    sq  += v2.x * v2.x + v2.y * v2.y + v2.z * v2.z + v2.w * v2.w;
  }
  for (int off = 32; off > 0; off >>= 1) {
    sum += __shfl_xor(sum, off, 64);
    sq  += __shfl_xor(sq, off, 64);
  }
  const float mean = sum * (1.0f / NH);
  const float var  = sq * (1.0f / NH) - mean * mean;
  const float rstd = rsqrtf(var + 1e-12f);
  const float4* wr = (const float4*)(wt + (size_t)b * NH);
  const float4* br = (const float4*)(bs + (size_t)b * NH);
  ushort4* xr = (ushort4*)(xbf + (size_t)row * NH);
#pragma unroll
  for (int i = 0; i < 3; i++) {
    float4 v = (i == 0) ? v0 : (i == 1) ? v1 : v2;
    float4 w = wr[lane + 64 * i];
    float4 bb = br[lane + 64 * i];
    ushort4 o;
    o.x = f2bf((v.x - mean) * rstd * w.x + bb.x);
    o.y = f2bf((v.y - mean) * rstd * w.y + bb.y);
    o.z = f2bf((v.z - mean) * rstd * w.z + bb.z);
    o.w = f2bf((v.w - mean) * rstd * w.w + bb.w);
    xr[lane + 64 * i] = o;
  }
}

// ---------------- weight prep: Wq/Wk/Wv -> bf16 concat ----------------
__launch_bounds__(256)
__global__ void prep_w(const float* __restrict__ Wq, const float* __restrict__ bq,
                       const float* __restrict__ Wk, const float* __restrict__ bk,
                       const float* __restrict__ Wv, const float* __restrict__ bv,
                       unsigned short* __restrict__ Wcat, float* __restrict__ bcat) {
  const int row = blockIdx.x;  // 0..2303
  const float* Wsrc;
  const float* bsrc;
  int r;
  if (row < NH) { Wsrc = Wq; bsrc = bq; r = row; }
  else if (row < NH2) { Wsrc = Wk; bsrc = bk; r = row - NH; }
  else { Wsrc = Wv; bsrc = bv; r = row - NH2; }
  for (int j = threadIdx.x; j < NH; j += 256)
    Wcat[(size_t)row * NH + j] = f2bf(Wsrc[(size_t)r * NH + j]);
  if (threadIdx.x == 0) bcat[row] = bsrc[r];
}

// ============ TM x 256 BK=64 8-wave GEMM, phased schedule ============
// C = op(A @ B^T).  TM=256 (4-phase vmcnt(6)) or TM=128 (2-phase vmcnt(4)).
// OUTMODE: 0=f32, 1=bf16, 2=f16. SPLIT3: q,k compact; v -> vT via LDS-staged
// transpose + coalesced stores. MASKB (scores): x -= 1e10*(1-mask[col]) so
// masked f16 scores saturate to -inf. PVEXP (PV): A operand is raw masked
// f16 scores; fragments are transformed in-register p=bf16(exp(e-rowmax))
// (rowmax per-lane scalar, rows fixed per fragment) and the epilogue scales
// by rowinv (softmax denominator commutes out of the V-contraction).
// FPRED: fused head projection -> atomicAdd into pred.
template <int TM, int OUTMODE, int RELU, int HASBIAS, int RES, int SPLIT3,
          int FPRED, int MASKB, int PVEXP>
__launch_bounds__(512, 2)
__global__ void gemm256(const unsigned short* __restrict__ A, long long sAz, int lda,
                        const unsigned short* __restrict__ Bm, long long sBz, int ldb,
                        void* __restrict__ C, long long sCz, int ldc,
                        const float* __restrict__ bias,
                        const unsigned short* __restrict__ Res, long long sRz, int ldr,
                        int K, unsigned short* __restrict__ vTp,
                        const float* __restrict__ maskp,
                        const float* __restrict__ rmax,
                        const float* __restrict__ rinv,
                        const float* __restrict__ wobj,
                        const float* __restrict__ bobj,
                        float* __restrict__ pred) {
  extern __shared__ char lds[];
  const int t = threadIdx.x;
  const int z = blockIdx.z;
  // bijective XCD-aware swizzle over the xy-grid (per z)
  int id = blockIdx.x + blockIdx.y * gridDim.x;
  {
    const int nwg = gridDim.x * gridDim.y;
    const int q = nwg >> 3, r = nwg & 7;
    const int xcd = id & 7, lid = id >> 3;
    id = (xcd < r ? xcd * (q + 1) : r * (q + 1) + (xcd - r) * q) + lid;
  }
  const int tileN = (id % gridDim.x) * 256;
  const int tileM = (id / gridDim.x) * TM;
  const unsigned short* Ab = A + (size_t)z * sAz + (size_t)tileM * lda;
  const unsigned short* Bb = Bm + (size_t)z * sBz + (size_t)tileN * ldb;

  const int lane = t & 63;
  const int w = t >> 6;
  const int wmr = w >> 2, wn = w & 3;      // wave grid 2M x 4N
  const int lr = lane & 15, hi = lane >> 4;
  const int swz = (lr & 7) << 4;           // row-derived byte XOR
  const int brow0 = (wn & 1) * 64;         // B row offset within half
  const int arow0 = (TM == 128) ? wmr * 64 : 0;
  constexpr int BBASE = (TM == 256) ? 65536 : 32768;  // B region base

  const int sr = t >> 3;
  const int scc = (t & 7) ^ (sr & 7);

  // PVEXP: per-lane row stats (rows fixed per A fragment: arow0+m*16+lr)
  float mxv[4];
  if (PVEXP) {
#pragma unroll
    for (int m = 0; m < 4; m++)
      mxv[m] = rmax[(size_t)z * NS + tileM + arow0 + m * 16 + lr];
  }

#define STAGEH(Gb, ld, kc, dst)                                             \
  do {                                                                      \
    GLDS16((Gb) + (size_t)sr * (ld) + (kc) + scc * 8, (dst) + (size_t)t * 16); \
    GLDS16((Gb) + (size_t)(64 + sr) * (ld) + (kc) + scc * 8,                \
           (dst) + 8192 + (size_t)t * 16);                                  \
  } while (0)

#define RD_BALL(Bh)                                                         \
  do {                                                                      \
    _Pragma("unroll") for (int nn_ = 0; nn_ < 4; nn_++)                     \
      _Pragma("unroll") for (int ks_ = 0; ks_ < 2; ks_++)                   \
        bF[nn_][ks_] = *(const bf16x8*)((Bh) + (brow0 + nn_ * 16 + lr) * 128 + \
                                        ((ks_ * 64 + hi * 16) ^ swz));      \
  } while (0)

#define RD_AH(m0, Ah)                                                       \
  do {                                                                      \
    _Pragma("unroll") for (int mm_ = 0; mm_ < 4; mm_++)                     \
      _Pragma("unroll") for (int ks_ = 0; ks_ < 2; ks_++) {                 \
        const char* ap_ = (Ah) + ((arow0 + (m0) * 16 + mm_ * 16 + lr) * 128) + \
                          ((ks_ * 64 + hi * 16) ^ swz);                     \
        if (PVEXP) {                                                        \
          f16x8 raw_ = *(const f16x8*)ap_;                                  \
          u16x8 pb_;                                                        \
          _Pragma("unroll") for (int j_ = 0; j_ < 8; j_++)                  \
            pb_[j_] = f2bf(__expf((float)raw_[j_] - mxv[mm_]));             \
          aF[mm_][ks_] = __builtin_bit_cast(bf16x8, pb_);                   \
        } else {                                                            \
          aF[mm_][ks_] = *(const bf16x8*)ap_;                               \
        }                                                                   \
      }                                                                     \
  } while (0)

#define MFMAQ(mb, nb)                                                       \
  do {                                                                      \
    __builtin_amdgcn_s_setprio(1);                                          \
    _Pragma("unroll") for (int ks_ = 0; ks_ < 2; ks_++)                     \
      _Pragma("unroll") for (int mm_ = 0; mm_ < 4; mm_++)                   \
        _Pragma("unroll") for (int nn_ = 0; nn_ < 2; nn_++)                 \
          acc[(mb) + mm_][(nb) + nn_] = __builtin_amdgcn_mfma_f32_16x16x32_bf16( \
              aF[mm_][ks_], bF[(nb) + nn_][ks_], acc[(mb) + mm_][(nb) + nn_], \
              0, 0, 0);                                                     \
    __builtin_amdgcn_s_setprio(0);                                          \
  } while (0)

  f32x4 acc[TM / 32][4];
#pragma unroll
  for (int m = 0; m < TM / 32; m++)
#pragma unroll
    for (int n = 0; n < 4; n++) acc[m][n] = (f32x4)0.0f;

  const int NT = K >> 6;  // K-tiles of 64 (>=2)

  if (TM == 256) {
    STAGEH(Bb, ldb, 0, lds + BBASE);
    STAGEH(Bb + (size_t)128 * ldb, ldb, 0, lds + BBASE + 16384);
    STAGEH(Ab, lda, 0, lds);
    STAGEH(Ab + (size_t)128 * lda, lda, 0, lds + 16384);
    STAGEH(Bb, ldb, 64, lds + BBASE + 32768);
    STAGEH(Bb + (size_t)128 * ldb, ldb, 64, lds + BBASE + 32768 + 16384);
    STAGEH(Ab, lda, 64, lds + 32768);
    WAITVM6();
    SBAR();
    for (int kt = 0; kt < NT; kt++) {
      const int bc = kt & 1;
      const char* Ah = lds + bc * 32768 + wmr * 16384;
      const char* Bh = lds + BBASE + bc * 32768 + (wn >> 1) * 16384;
      bf16x8 aF[4][2], bF[4][2];
      RD_BALL(Bh);
      RD_AH(0, Ah);
      if (kt + 1 < NT)
        STAGEH(Ab + (size_t)128 * lda, lda, (kt + 1) * 64,
               lds + (bc ^ 1) * 32768 + 16384);
      SBAR();
      LGKM0();
      MFMAQ(0, 0);
      SBAR();
      if (kt + 2 < NT)
        STAGEH(Bb, ldb, (kt + 2) * 64, lds + BBASE + bc * 32768);
      SBAR();
      MFMAQ(0, 2);
      SBAR();
      RD_AH(4, Ah);
      if (kt + 2 < NT)
        STAGEH(Bb + (size_t)128 * ldb, ldb, (kt + 2) * 64,
               lds + BBASE + bc * 32768 + 16384);
      SBAR();
      LGKM0();
      MFMAQ(4, 2);
      SBAR();
      if (kt + 2 < NT)
        STAGEH(Ab, lda, (kt + 2) * 64, lds + bc * 32768);
      SBAR();
      MFMAQ(4, 0);
      if (kt + 2 < NT) {
        WAITVM6();
      } else if (kt + 1 < NT) {
        WAITVM0();
      }
      SBAR();
    }
  } else {
    STAGEH(Bb, ldb, 0, lds + BBASE);
    STAGEH(Bb + (size_t)128 * ldb, ldb, 0, lds + BBASE + 16384);
    STAGEH(Ab, lda, 0, lds);
    STAGEH(Bb, ldb, 64, lds + BBASE + 32768);
    STAGEH(Bb + (size_t)128 * ldb, ldb, 64, lds + BBASE + 32768 + 16384);
    WAITVM4();
    SBAR();
    for (int kt = 0; kt < NT; kt++) {
      const int bc = kt & 1;
      const char* Ah = lds + bc * 16384;
      const char* Bh = lds + BBASE + bc * 32768 + (wn >> 1) * 16384;
      bf16x8 aF[4][2], bF[4][2];
      RD_BALL(Bh);
      RD_AH(0, Ah);
      if (kt + 1 < NT)
        STAGEH(Ab, lda, (kt + 1) * 64, lds + (bc ^ 1) * 16384);
      SBAR();
      LGKM0();
      MFMAQ(0, 0);
      SBAR();
      if (kt + 2 < NT) {
        STAGEH(Bb, ldb, (kt + 2) * 64, lds + BBASE + bc * 32768);
        STAGEH(Bb + (size_t)128 * ldb, ldb, (kt + 2) * 64,
               lds + BBASE + bc * 32768 + 16384);
      }
      SBAR();
      MFMAQ(0, 2);
      if (kt + 2 < NT) {
        WAITVM4();
      } else if (kt + 1 < NT) {
        WAITVM0();
      }
      SBAR();
    }
  }

  // epilogue: C/D layout col=lane&15, row=(lane>>4)*4+reg  [m89-verified]
  const int row0 = tileM + wmr * ((TM == 256) ? 128 : 64);
  const int col0 = tileN + wn * 64;

  if (SPLIT3 && tileN >= NH2) {
    // ---- v-tile: LDS-staged transpose -> coalesced stores to vT ----
    unsigned short* lt = (unsigned short*)lds;  // [128 cols][264 u16] = 66KB
    const int bz = tileM >> 10;
    const int sbase = tileM & (NS - 1);
    const int myhalf = wn >> 1;
#pragma unroll
    for (int half = 0; half < 2; half++) {
      if (myhalf == half) {
#pragma unroll
        for (int m = 0; m < TM / 32; m++) {
          const int lrow = (row0 - tileM) + m * 16 + hi * 4;
#pragma unroll
          for (int n = 0; n < 4; n++) {
            const int lcol = (wn & 1) * 64 + n * 16 + lr;
            const float bv = HASBIAS ? bias[col0 + n * 16 + lr] : 0.0f;
            f32x4 v = acc[m][n];
#pragma unroll
            for (int r = 0; r < 4; r++) {
              float x = v[r] + bv;
              if (RELU) x = fmaxf(x, 0.0f);
              lt[lcol * 264 + lrow + r] = f2bf(x);
            }
          }
        }
      }
      SBAR();
      {
        const int h = t >> 2;
        const int hglob = (tileN - NH2) + half * 128 + h;
        unsigned short* dst =
            vTp + ((size_t)bz * NH + hglob) * NS + sbase;
#pragma unroll
        for (int it = 0; it < 8; it++) {
          const int s = (t & 3) * 8 + it * 32;
          u16x8 vv = *(const u16x8*)&lt[h * 264 + s];
          *(u16x8*)(dst + s) = vv;
        }
      }
      SBAR();
    }
  } else {
#pragma unroll
    for (int m = 0; m < TM / 32; m++) {
      const int rowb = row0 + m * 16 + hi * 4;
      float psum[4] = {0.f, 0.f, 0.f, 0.f};
      float4 isv;
      if (PVEXP)
        isv = *(const float4*)(rinv + (size_t)z * NS + rowb);
#pragma unroll
      for (int n = 0; n < 4; n++) {
        const int col = col0 + n * 16 + lr;
        const float bv = HASBIAS ? bias[col] : 0.0f;
        f32x4 v = acc[m][n];
#pragma unroll
        for (int r = 0; r < 4; r++) {
          float x = v[r] + bv;
          if (PVEXP) x *= ((const float*)&isv)[r];
          if (RELU) x = fmaxf(x, 0.0f);
          if (MASKB) x -= 1e10f * (1.0f - maskp[(size_t)z * NS + col]);
          if (RES)
            x += bf2f(Res[(size_t)z * sRz + (size_t)(rowb + r) * ldr + col]);
          if (SPLIT3) {
            const int seg = col >= NH ? 1 : 0;  // v handled above
            ((unsigned short*)C)[(size_t)seg * NBS * NH +
                                 (size_t)(rowb + r) * NH + (col - seg * NH)] =
                f2bf(x);
          } else if (OUTMODE == 1) {
            ((unsigned short*)C)[(size_t)z * sCz + (size_t)(rowb + r) * ldc +
                                 col] = f2bf(x);
          } else if (OUTMODE == 2) {
            ((_Float16*)C)[(size_t)z * sCz + (size_t)(rowb + r) * ldc + col] =
                (_Float16)x;
          } else {
            ((float*)C)[(size_t)z * sCz + (size_t)(rowb + r) * ldc + col] = x;
          }
          if (FPRED) psum[r] += x * wobj[col];
        }
      }
      if (FPRED) {
#pragma unroll
        for (int r = 0; r < 4; r++) {
          float s = psum[r];
          s += __shfl_xor(s, 1, 64);
          s += __shfl_xor(s, 2, 64);
          s += __shfl_xor(s, 4, 64);
          s += __shfl_xor(s, 8, 64);
          if (lr == 0) {
            float add = s + ((tileN == 0 && wn == 0) ? bobj[0] : 0.0f);
            atomicAdd(pred + (size_t)z * NS + rowb + r, add);
          }
        }
      }
    }
  }
#undef STAGEH
#undef RD_BALL
#undef RD_AH
#undef MFMAQ
}

// ------------- rowstats: masked f16 score rows -> (max, 1/sum) -------------
__launch_bounds__(256)
__global__ void rowstats_kernel(const _Float16* __restrict__ e,
                                float* __restrict__ rmax,
                                float* __restrict__ rinv) {
  const int ri = blockIdx.x;
  const int lb = blockIdx.y;
  const _Float16* row = e + ((size_t)lb * NS + ri) * NS;
  const int t = threadIdx.x;
  f16x4 u = ((const f16x4*)row)[t];
  float v0 = (float)u[0], v1 = (float)u[1], v2 = (float)u[2], v3 = (float)u[3];
  float mx = fmaxf(fmaxf(v0, v1), fmaxf(v2, v3));
  __shared__ float red[4];
  for (int off = 32; off > 0; off >>= 1) mx = fmaxf(mx, __shfl_xor(mx, off, 64));
  if ((t & 63) == 0) red[t >> 6] = mx;
  __syncthreads();
  mx = fmaxf(fmaxf(red[0], red[1]), fmaxf(red[2], red[3]));
  float sm = __expf(v0 - mx) + __expf(v1 - mx) + __expf(v2 - mx) +
             __expf(v3 - mx);
  __syncthreads();
  for (int off = 32; off > 0; off >>= 1) sm += __shfl_xor(sm, off, 64);
  if ((t & 63) == 0) red[t >> 6] = sm;
  __syncthreads();
  if (t == 0) {
    sm = red[0] + red[1] + red[2] + red[3];
    rmax[(size_t)lb * NS + ri] = mx;
    rinv[(size_t)lb * NS + ri] = 1.0f / sm;
  }
}

// ---------------- launcher ----------------
extern "C" void kernel_launch(void* const* d_in, const int* in_sizes, int n_in,
                              void* d_out, int out_size, void* d_ws,
                              size_t ws_size, hipStream_t stream) {
  const int* relation   = (const int*)d_in[0];
  const float* lhs      = (const float*)d_in[1];
  const int* sub_head   = (const int*)d_in[2];
  const int* sub_tail   = (const int*)d_in[3];
  const float* att_mask = (const float*)d_in[4];
  const float* rel_emb  = (const float*)d_in[5];
  const float* W_rf     = (const float*)d_in[6];
  const float* b_rf     = (const float*)d_in[7];
  const float* gamma    = (const float*)d_in[8];
  const float* beta     = (const float*)d_in[9];
  const float* W_wd     = (const float*)d_in[10];
  const float* W_bd     = (const float*)d_in[11];
  const float* Wq       = (const float*)d_in[12];
  const float* bq       = (const float*)d_in[13];
  const float* Wk       = (const float*)d_in[14];
  const float* bk       = (const float*)d_in[15];
  const float* Wv       = (const float*)d_in[16];
  const float* bv       = (const float*)d_in[17];
  const float* W_obj    = (const float*)d_in[18];
  const float* b_obj    = (const float*)d_in[19];

  char* ws = (char*)d_ws;
  // offsets (all 256B aligned)
  unsigned short* Wcat = (unsigned short*)(ws + 0);          //  3,538,944
  float* bcat  = (float*)(ws + 3538944);                     //      9,216
  float* wt    = (float*)(ws + 3548160);                     //     98,304
  float* bs    = (float*)(ws + 3646464);                     //     98,304
  float* reT   = (float*)(ws + 3744768);                     //     98,304
  float* condT = (float*)(ws + 3843072);                     //    196,608
  unsigned short* xbf = (unsigned short*)(ws + 4039680);     // 50,331,648
  unsigned short* qkv = (unsigned short*)(ws + 54371328);    // 100,663,296 (q|k compact)
  unsigned short* vT  = (unsigned short*)(ws + 155034624);   // 50,331,648
  char* attbuf = ws + 205366272;                             // CB*(2MB e) + stats

  float* out_pred = (float*)d_out;
  float* out_hidden = out_pred + NBS;

  const size_t fixed = 205366272ull;
  size_t avail = ws_size > fixed ? ws_size - fixed : 0;
  int CB = 32;
  while (CB > 1 &&
         (size_t)CB * ((size_t)NS * NS * 2 + (size_t)NS * 8) > avail)
    CB >>= 1;
  _Float16* ebuf = (_Float16*)attbuf;                         // CB*2,097,152
  float* rmax = (float*)(attbuf + (size_t)CB * NS * NS * 2);  // CB*4096
  float* rinv = rmax + (size_t)CB * NS;                       // CB*4096

  prep_w<<<dim3(NQKV), dim3(256), 0, stream>>>(Wq, bq, Wk, bk, Wv, bv, Wcat, bcat);
  cond_pre<<<dim3(NB), dim3(256), 0, stream>>>(relation, lhs, sub_head, sub_tail,
                                               rel_emb, reT, condT);
  cond_rf<<<dim3(NH / 8), dim3(256), 0, stream>>>(W_rf, b_rf, reT, condT);
  cond_wb<<<dim3(NH / 4), dim3(256), 0, stream>>>(W_wd, W_bd, gamma, beta, condT,
                                                  wt, bs);
  ln_kernel<<<dim3(NBS), dim3(64), 0, stream>>>(lhs, wt, bs, xbf);
  hipMemsetAsync(out_pred, 0, (size_t)NBS * sizeof(float), stream);

  // QKV: q,k compact; v -> vT via LDS-staged transpose
  gemm256<256, 1, 1, 1, 0, 1, 0, 0, 0>
      <<<dim3(NQKV / 256, NBS / 256, 1), dim3(512), 131072, stream>>>(
          xbf, 0, NH, Wcat, 0, NH, qkv, 0, NH, bcat, nullptr, 0, 0, NH, vT,
          nullptr, nullptr, nullptr, nullptr, nullptr, nullptr);

  for (int b0 = 0; b0 < NB; b0 += CB) {
    // scores: e = q_c @ k_c^T - 1e10*(1-mask)  (f16 out; masked -> -inf)
    gemm256<256, 2, 0, 0, 0, 0, 0, 1, 0>
        <<<dim3(NS / 256, NS / 256, CB), dim3(512), 131072, stream>>>(
            qkv + (size_t)b0 * NS * NH, (long long)NS * NH, NH,
            qkv + (size_t)NBS * NH + (size_t)b0 * NS * NH, (long long)NS * NH, NH,
            ebuf, (long long)NS * NS, NS, nullptr, nullptr, 0, 0, NH, nullptr,
            att_mask + (size_t)b0 * NS, nullptr, nullptr, nullptr, nullptr,
            nullptr);
    // rowstats: per-row max and 1/sum of exp
    rowstats_kernel<<<dim3(NS, CB), dim3(256), 0, stream>>>(ebuf, rmax, rinv);
    // hidden = softmax(e) @ v + x : PVEXP transforms A-fragments in-register,
    // epilogue scales by rowinv; fused head projection
    gemm256<128, 0, 0, 0, 1, 0, 1, 0, 1>
        <<<dim3(NH / 256, NS / 128, CB), dim3(512), 98304, stream>>>(
            (const unsigned short*)ebuf, (long long)NS * NS, NS,
            vT + (size_t)b0 * NH * NS, (long long)NH * NS, NS,
            out_hidden + (size_t)b0 * NS * NH, (long long)NS * NH, NH, nullptr,
            xbf + (size_t)b0 * NS * NH, (long long)NS * NH, NH, NS, nullptr,
            nullptr, rmax, rinv, W_obj, b_obj, out_pred + (size_t)b0 * NS);
  }
}

// Round 18
// 453.980 us; speedup vs baseline: 1.0848x; 1.0848x over previous
//
#include <hip/hip_runtime.h>

// ---------------- problem constants ----------------
constexpr int NB  = 32;     // batch
constexpr int NS  = 1024;   // seq
constexpr int NH  = 768;    // hidden
constexpr int NH2 = 1536;   // 2*hidden
constexpr int NQKV = 2304;  // 3*hidden
constexpr int NBS = NB * NS;

typedef __bf16 bf16x8 __attribute__((ext_vector_type(8)));
typedef float  f32x4  __attribute__((ext_vector_type(4)));
typedef unsigned short u16x8 __attribute__((ext_vector_type(8)));

__device__ __forceinline__ unsigned short f2bf(float f) {
  unsigned int u = __builtin_bit_cast(unsigned int, f);
  u += 0x7FFFu + ((u >> 16) & 1u);
  return (unsigned short)(u >> 16);
}
__device__ __forceinline__ float bf2f(unsigned short h) {
  return __builtin_bit_cast(float, ((unsigned int)h) << 16);
}

#define GLDS16(g, l)                                                         \
  __builtin_amdgcn_global_load_lds(                                          \
      (__attribute__((address_space(1))) void*)(g),                          \
      (__attribute__((address_space(3))) void*)(l), 16, 0, 0)

#define SBAR()    asm volatile("s_barrier" ::: "memory")
#define WAITVM6() asm volatile("s_waitcnt vmcnt(6)" ::: "memory")
#define WAITVM4() asm volatile("s_waitcnt vmcnt(4)" ::: "memory")
#define WAITVM0() asm volatile("s_waitcnt vmcnt(0)" ::: "memory")
#define LGKM0()                                                              \
  do {                                                                       \
    asm volatile("s_waitcnt lgkmcnt(0)" ::: "memory");                       \
    __builtin_amdgcn_sched_barrier(0);                                       \
  } while (0)

// ---------------- cond stage 0: gather + transpose ----------------
__launch_bounds__(256)
__global__ void cond_pre(const int* __restrict__ relation,
                         const float* __restrict__ h,
                         const int* __restrict__ subh,
                         const int* __restrict__ subt,
                         const float* __restrict__ rel_emb,
                         float* __restrict__ reT, float* __restrict__ condT) {
  const int b = blockIdx.x, t = threadIdx.x;
  const int r = relation[b], sh = subh[b], st = subt[b];
  for (int k = t; k < NH; k += 256) {
    reT[(size_t)k * NB + b] = rel_emb[(size_t)r * NH + k];
    condT[(size_t)(NH + k) * NB + b] =
        0.5f * (h[((size_t)b * NS + sh) * NH + k] +
                h[((size_t)b * NS + st) * NH + k]);
  }
}

// ---------------- cond stage 1: rel_feature = relu6(re @ W_rf^T + b_rf) ----
__launch_bounds__(256)
__global__ void cond_rf(const float* __restrict__ W_rf,
                        const float* __restrict__ b_rf,
                        const float* __restrict__ reT,
                        float* __restrict__ condT) {
  const int t = threadIdx.x;
  const int b = t & 31, jl = t >> 5;
  const int j = blockIdx.x * 8 + jl;
  const float4* w4 = (const float4*)(W_rf + (size_t)j * NH);
  const float* rT = reT + b;
  float a0 = 0.f, a1 = 0.f;
  for (int k4 = 0; k4 < NH / 4; k4++) {
    float4 w = w4[k4];
    const float* c = rT + (size_t)(k4 * 4) * NB;
    a0 += w.x * c[0] + w.y * c[NB];
    a1 += w.z * c[2 * NB] + w.w * c[3 * NB];
  }
  float acc = a0 + a1 + b_rf[j];
  condT[(size_t)j * NB + b] = fminf(fmaxf(acc, 0.0f), 6.0f);
}

// ---------------- cond stage 2: wt/bs = cond @ W_{wd,bd}^T + gamma/beta ----
__launch_bounds__(256)
__global__ void cond_wb(const float* __restrict__ W_wd,
                        const float* __restrict__ W_bd,
                        const float* __restrict__ gamma,
                        const float* __restrict__ beta,
                        const float* __restrict__ condT,
                        float* __restrict__ wt, float* __restrict__ bs) {
  __shared__ float redW[128], redB[128];
  const int t = threadIdx.x;
  const int b = t & 31, jl = (t >> 5) & 3, ks = t >> 7;
  const int j = blockIdx.x * 4 + jl;
  const float4* ww = (const float4*)(W_wd + (size_t)j * NH2 + ks * NH);
  const float4* wb = (const float4*)(W_bd + (size_t)j * NH2 + ks * NH);
  const float* cT = condT + (size_t)ks * NH * NB + b;
  float aw0 = 0.f, aw1 = 0.f, ab0 = 0.f, ab1 = 0.f;
  for (int k4 = 0; k4 < NH / 4; k4++) {
    float4 w = ww[k4];
    float4 v = wb[k4];
    const float* c = cT + (size_t)(k4 * 4) * NB;
    float c0 = c[0], c1 = c[NB], c2 = c[2 * NB], c3 = c[3 * NB];
    aw0 += w.x * c0 + w.y * c1;
    aw1 += w.z * c2 + w.w * c3;
    ab0 += v.x * c0 + v.y * c1;
    ab1 += v.z * c2 + v.w * c3;
  }
  float aw = aw0 + aw1, ab = ab0 + ab1;
  if (ks == 1) {
    redW[t - 128] = aw;
    redB[t - 128] = ab;
  }
  __syncthreads();
  if (ks == 0) {
    aw += redW[t];
    ab += redB[t];
    wt[(size_t)b * NH + j] = aw + gamma[j];
    bs[(size_t)b * NH + j] = ab + beta[j];
  }
}

// ---------------- conditional layernorm -> x (bf16) ----------------
__launch_bounds__(64)
__global__ void ln_kernel(const float* __restrict__ h,
                          const float* __restrict__ wt,
                          const float* __restrict__ bs,
                          unsigned short* __restrict__ xbf) {
  const int row = blockIdx.x;      // 0..NBS-1
  const int b = row >> 10;
  const int lane = threadIdx.x;    // 0..63
  const float4* hr = (const float4*)(h + (size_t)row * NH);
  float4 v0 = hr[lane], v1 = hr[lane + 64], v2 = hr[lane + 128];
  float sum = 0.f, sq = 0.f;
  {
    sum += v0.x + v0.y + v0.z + v0.w;
    sq  += v0.x * v0.x + v0.y * v0.y + v0.z * v0.z + v0.w * v0.w;
    sum += v1.x + v1.y + v1.z + v1.w;
    sq  += v1.x * v1.x + v1.y * v1.y + v1.z * v1.z + v1.w * v1.w;
    sum += v2.x + v2.y + v2.z + v2.w;
    sq  += v2.x * v2.x + v2.y * v2.y + v2.z * v2.z + v2.w * v2.w;
  }
  for (int off = 32; off > 0; off >>= 1) {
    sum += __shfl_xor(sum, off, 64);
    sq  += __shfl_xor(sq, off, 64);
  }
  const float mean = sum * (1.0f / NH);
  const float var  = sq * (1.0f / NH) - mean * mean;
  const float rstd = rsqrtf(var + 1e-12f);
  const float4* wr = (const float4*)(wt + (size_t)b * NH);
  const float4* br = (const float4*)(bs + (size_t)b * NH);
  ushort4* xr = (ushort4*)(xbf + (size_t)row * NH);
#pragma unroll
  for (int i = 0; i < 3; i++) {
    float4 v = (i == 0) ? v0 : (i == 1) ? v1 : v2;
    float4 w = wr[lane + 64 * i];
    float4 bb = br[lane + 64 * i];
    ushort4 o;
    o.x = f2bf((v.x - mean) * rstd * w.x + bb.x);
    o.y = f2bf((v.y - mean) * rstd * w.y + bb.y);
    o.z = f2bf((v.z - mean) * rstd * w.z + bb.z);
    o.w = f2bf((v.w - mean) * rstd * w.w + bb.w);
    xr[lane + 64 * i] = o;
  }
}

// ---------------- weight prep: Wq/Wk/Wv -> bf16 concat ----------------
__launch_bounds__(256)
__global__ void prep_w(const float* __restrict__ Wq, const float* __restrict__ bq,
                       const float* __restrict__ Wk, const float* __restrict__ bk,
                       const float* __restrict__ Wv, const float* __restrict__ bv,
                       unsigned short* __restrict__ Wcat, float* __restrict__ bcat) {
  const int row = blockIdx.x;  // 0..2303
  const float* Wsrc;
  const float* bsrc;
  int r;
  if (row < NH) { Wsrc = Wq; bsrc = bq; r = row; }
  else if (row < NH2) { Wsrc = Wk; bsrc = bk; r = row - NH; }
  else { Wsrc = Wv; bsrc = bv; r = row - NH2; }
  for (int j = threadIdx.x; j < NH; j += 256)
    Wcat[(size_t)row * NH + j] = f2bf(Wsrc[(size_t)r * NH + j]);
  if (threadIdx.x == 0) bcat[row] = bsrc[r];
}

// ============ TM x 256 BK=64 8-wave GEMM, phased schedule ============
// C = op(A @ B^T).  A:[M,K] bf16 lda; B:[N,K] bf16 ldb; C:[M,N].
// TM=256 (R8 4-phase, vmcnt(6), LDS 128K) or TM=128 (2-phase, vmcnt(4)).
// OUTMODE: 0=f32, 1=bf16, 2=f16. SPLIT3 (QKV): q,k cols -> compact
// [NBS][NH] bf16; v cols (tileN>=NH2, whole tiles) -> LDS-staged transpose
// then COALESCED 16B stores direct to vT[b][h][s].
// FPRED (PV): fused head projection -> atomicAdd into pred.
// (R17 lesson: exp inside the K-loop operand path makes PV VALU-bound,
// MfmaUtil 31->12; keep softmax as a separate memory-bound pass.)
template <int TM, int OUTMODE, int RELU, int HASBIAS, int RES, int SPLIT3,
          int FPRED>
__launch_bounds__(512, 2)
__global__ void gemm256(const unsigned short* __restrict__ A, long long sAz, int lda,
                        const unsigned short* __restrict__ Bm, long long sBz, int ldb,
                        void* __restrict__ C, long long sCz, int ldc,
                        const float* __restrict__ bias,
                        const unsigned short* __restrict__ Res, long long sRz, int ldr,
                        int K, unsigned short* __restrict__ vTp,
                        const float* __restrict__ wobj,
                        const float* __restrict__ bobj,
                        float* __restrict__ pred) {
  extern __shared__ char lds[];
  const int t = threadIdx.x;
  const int z = blockIdx.z;
  // bijective XCD-aware swizzle over the xy-grid (per z)
  int id = blockIdx.x + blockIdx.y * gridDim.x;
  {
    const int nwg = gridDim.x * gridDim.y;
    const int q = nwg >> 3, r = nwg & 7;
    const int xcd = id & 7, lid = id >> 3;
    id = (xcd < r ? xcd * (q + 1) : r * (q + 1) + (xcd - r) * q) + lid;
  }
  const int tileN = (id % gridDim.x) * 256;
  const int tileM = (id / gridDim.x) * TM;
  const unsigned short* Ab = A + (size_t)z * sAz + (size_t)tileM * lda;
  const unsigned short* Bb = Bm + (size_t)z * sBz + (size_t)tileN * ldb;

  const int lane = t & 63;
  const int w = t >> 6;
  const int wmr = w >> 2, wn = w & 3;      // wave grid 2M x 4N
  const int lr = lane & 15, hi = lane >> 4;
  const int swz = (lr & 7) << 4;           // row-derived byte XOR
  const int brow0 = (wn & 1) * 64;         // B row offset within half
  const int arow0 = (TM == 128) ? wmr * 64 : 0;
  constexpr int BBASE = (TM == 256) ? 65536 : 32768;  // B region base

  const int sr = t >> 3;
  const int scc = (t & 7) ^ (sr & 7);

#define STAGEH(Gb, ld, kc, dst)                                             \
  do {                                                                      \
    GLDS16((Gb) + (size_t)sr * (ld) + (kc) + scc * 8, (dst) + (size_t)t * 16); \
    GLDS16((Gb) + (size_t)(64 + sr) * (ld) + (kc) + scc * 8,                \
           (dst) + 8192 + (size_t)t * 16);                                  \
  } while (0)

#define RD_BALL(Bh)                                                         \
  do {                                                                      \
    _Pragma("unroll") for (int nn_ = 0; nn_ < 4; nn_++)                     \
      _Pragma("unroll") for (int ks_ = 0; ks_ < 2; ks_++)                   \
        bF[nn_][ks_] = *(const bf16x8*)((Bh) + (brow0 + nn_ * 16 + lr) * 128 + \
                                        ((ks_ * 64 + hi * 16) ^ swz));      \
  } while (0)

#define RD_AH(m0, Ah)                                                       \
  do {                                                                      \
    _Pragma("unroll") for (int mm_ = 0; mm_ < 4; mm_++)                     \
      _Pragma("unroll") for (int ks_ = 0; ks_ < 2; ks_++)                   \
        aF[mm_][ks_] = *(const bf16x8*)((Ah) + ((arow0 + (m0) * 16 + mm_ * 16 + lr) * 128) + \
                                        ((ks_ * 64 + hi * 16) ^ swz));      \
  } while (0)

#define MFMAQ(mb, nb)                                                       \
  do {                                                                      \
    __builtin_amdgcn_s_setprio(1);                                          \
    _Pragma("unroll") for (int ks_ = 0; ks_ < 2; ks_++)                     \
      _Pragma("unroll") for (int mm_ = 0; mm_ < 4; mm_++)                   \
        _Pragma("unroll") for (int nn_ = 0; nn_ < 2; nn_++)                 \
          acc[(mb) + mm_][(nb) + nn_] = __builtin_amdgcn_mfma_f32_16x16x32_bf16( \
              aF[mm_][ks_], bF[(nb) + nn_][ks_], acc[(mb) + mm_][(nb) + nn_], \
              0, 0, 0);                                                     \
    __builtin_amdgcn_s_setprio(0);                                          \
  } while (0)

  f32x4 acc[TM / 32][4];
#pragma unroll
  for (int m = 0; m < TM / 32; m++)
#pragma unroll
    for (int n = 0; n < 4; n++) acc[m][n] = (f32x4)0.0f;

  const int NT = K >> 6;  // K-tiles of 64 (>=2)

  if (TM == 256) {
    // prologue: B0(0),B1(0),A0(0),A1(0),B0(1),B1(1),A0(1); vmcnt(6)
    STAGEH(Bb, ldb, 0, lds + BBASE);
    STAGEH(Bb + (size_t)128 * ldb, ldb, 0, lds + BBASE + 16384);
    STAGEH(Ab, lda, 0, lds);
    STAGEH(Ab + (size_t)128 * lda, lda, 0, lds + 16384);
    STAGEH(Bb, ldb, 64, lds + BBASE + 32768);
    STAGEH(Bb + (size_t)128 * ldb, ldb, 64, lds + BBASE + 32768 + 16384);
    STAGEH(Ab, lda, 64, lds + 32768);
    WAITVM6();
    SBAR();
    for (int kt = 0; kt < NT; kt++) {
      const int bc = kt & 1;
      const char* Ah = lds + bc * 32768 + wmr * 16384;
      const char* Bh = lds + BBASE + bc * 32768 + (wn >> 1) * 16384;
      bf16x8 aF[4][2], bF[4][2];
      // ---- P1 ----
      RD_BALL(Bh);
      RD_AH(0, Ah);
      if (kt + 1 < NT)
        STAGEH(Ab + (size_t)128 * lda, lda, (kt + 1) * 64,
               lds + (bc ^ 1) * 32768 + 16384);
      SBAR();
      LGKM0();
      MFMAQ(0, 0);
      SBAR();
      // ---- P2 ----
      if (kt + 2 < NT)
        STAGEH(Bb, ldb, (kt + 2) * 64, lds + BBASE + bc * 32768);
      SBAR();
      MFMAQ(0, 2);
      SBAR();
      // ---- P3 ----
      RD_AH(4, Ah);
      if (kt + 2 < NT)
        STAGEH(Bb + (size_t)128 * ldb, ldb, (kt + 2) * 64,
               lds + BBASE + bc * 32768 + 16384);
      SBAR();
      LGKM0();
      MFMAQ(4, 2);
      SBAR();
      // ---- P4 ----
      if (kt + 2 < NT)
        STAGEH(Ab, lda, (kt + 2) * 64, lds + bc * 32768);
      SBAR();
      MFMAQ(4, 0);
      if (kt + 2 < NT) {
        WAITVM6();
      } else if (kt + 1 < NT) {
        WAITVM0();
      }
      SBAR();
    }
  } else {
    // TM == 128: 2 phases/K-tile.
    STAGEH(Bb, ldb, 0, lds + BBASE);
    STAGEH(Bb + (size_t)128 * ldb, ldb, 0, lds + BBASE + 16384);
    STAGEH(Ab, lda, 0, lds);
    STAGEH(Bb, ldb, 64, lds + BBASE + 32768);
    STAGEH(Bb + (size_t)128 * ldb, ldb, 64, lds + BBASE + 32768 + 16384);
    WAITVM4();
    SBAR();
    for (int kt = 0; kt < NT; kt++) {
      const int bc = kt & 1;
      const char* Ah = lds + bc * 16384;
      const char* Bh = lds + BBASE + bc * 32768 + (wn >> 1) * 16384;
      bf16x8 aF[4][2], bF[4][2];
      RD_BALL(Bh);
      RD_AH(0, Ah);
      if (kt + 1 < NT)
        STAGEH(Ab, lda, (kt + 1) * 64, lds + (bc ^ 1) * 16384);
      SBAR();
      LGKM0();
      MFMAQ(0, 0);
      SBAR();
      if (kt + 2 < NT) {
        STAGEH(Bb, ldb, (kt + 2) * 64, lds + BBASE + bc * 32768);
        STAGEH(Bb + (size_t)128 * ldb, ldb, (kt + 2) * 64,
               lds + BBASE + bc * 32768 + 16384);
      }
      SBAR();
      MFMAQ(0, 2);
      if (kt + 2 < NT) {
        WAITVM4();
      } else if (kt + 1 < NT) {
        WAITVM0();
      }
      SBAR();
    }
  }

  // epilogue: C/D layout col=lane&15, row=(lane>>4)*4+reg  [m89-verified]
  const int row0 = tileM + wmr * ((TM == 256) ? 128 : 64);
  const int col0 = tileN + wn * 64;

  if (SPLIT3 && tileN >= NH2) {
    // ---- v-tile: LDS-staged transpose -> coalesced stores to vT ----
    unsigned short* lt = (unsigned short*)lds;  // [128 cols][264 u16] = 66KB
    const int bz = tileM >> 10;
    const int sbase = tileM & (NS - 1);
    const int myhalf = wn >> 1;
#pragma unroll
    for (int half = 0; half < 2; half++) {
      if (myhalf == half) {
#pragma unroll
        for (int m = 0; m < TM / 32; m++) {
          const int lrow = (row0 - tileM) + m * 16 + hi * 4;
#pragma unroll
          for (int n = 0; n < 4; n++) {
            const int lcol = (wn & 1) * 64 + n * 16 + lr;
            const float bv = HASBIAS ? bias[col0 + n * 16 + lr] : 0.0f;
            f32x4 v = acc[m][n];
#pragma unroll
            for (int r = 0; r < 4; r++) {
              float x = v[r] + bv;
              if (RELU) x = fmaxf(x, 0.0f);
              lt[lcol * 264 + lrow + r] = f2bf(x);
            }
          }
        }
      }
      SBAR();
      {
        const int h = t >> 2;
        const int hglob = (tileN - NH2) + half * 128 + h;
        unsigned short* dst =
            vTp + ((size_t)bz * NH + hglob) * NS + sbase;
#pragma unroll
        for (int it = 0; it < 8; it++) {
          const int s = (t & 3) * 8 + it * 32;
          u16x8 vv = *(const u16x8*)&lt[h * 264 + s];
          *(u16x8*)(dst + s) = vv;
        }
      }
      SBAR();
    }
  } else {
#pragma unroll
    for (int m = 0; m < TM / 32; m++) {
      const int rowb = row0 + m * 16 + hi * 4;
      float psum[4] = {0.f, 0.f, 0.f, 0.f};
#pragma unroll
      for (int n = 0; n < 4; n++) {
        const int col = col0 + n * 16 + lr;
        const float bv = HASBIAS ? bias[col] : 0.0f;
        f32x4 v = acc[m][n];
#pragma unroll
        for (int r = 0; r < 4; r++) {
          float x = v[r] + bv;
          if (RELU) x = fmaxf(x, 0.0f);
          if (RES)
            x += bf2f(Res[(size_t)z * sRz + (size_t)(rowb + r) * ldr + col]);
          if (SPLIT3) {
            const int seg = col >= NH ? 1 : 0;  // v handled above
            ((unsigned short*)C)[(size_t)seg * NBS * NH +
                                 (size_t)(rowb + r) * NH + (col - seg * NH)] =
                f2bf(x);
          } else if (OUTMODE == 1) {
            ((unsigned short*)C)[(size_t)z * sCz + (size_t)(rowb + r) * ldc +
                                 col] = f2bf(x);
          } else if (OUTMODE == 2) {
            ((_Float16*)C)[(size_t)z * sCz + (size_t)(rowb + r) * ldc + col] =
                (_Float16)x;
          } else {
            ((float*)C)[(size_t)z * sCz + (size_t)(rowb + r) * ldc + col] = x;
          }
          if (FPRED) psum[r] += x * wobj[col];
        }
      }
      if (FPRED) {
#pragma unroll
        for (int r = 0; r < 4; r++) {
          float s = psum[r];
          s += __shfl_xor(s, 1, 64);
          s += __shfl_xor(s, 2, 64);
          s += __shfl_xor(s, 4, 64);
          s += __shfl_xor(s, 8, 64);
          if (lr == 0) {
            float add = s + ((tileN == 0 && wn == 0) ? bobj[0] : 0.0f);
            atomicAdd(pred + (size_t)z * NS + rowb + r, add);
          }
        }
      }
    }
  }
#undef STAGEH
#undef RD_BALL
#undef RD_AH
#undef MFMAQ
}

// ---------------- softmax (f16 row -> compact bf16 probs) ----------------
__launch_bounds__(256)
__global__ void softmax_kernel(const _Float16* __restrict__ e,
                               unsigned short* __restrict__ p,
                               const float* __restrict__ mask, int b0) {
  const int ri = blockIdx.x;
  const int lb = blockIdx.y;
  const int b = b0 + lb;
  const _Float16* row = e + ((size_t)lb * NS + ri) * NS;
  const int t = threadIdx.x;
  typedef _Float16 f16x4 __attribute__((ext_vector_type(4)));
  f16x4 u = ((const f16x4*)row)[t];
  float4 m = ((const float4*)(mask + (size_t)b * NS))[t];
  float v0 = (float)u[0] - 1e10f * (1.0f - m.x);
  float v1 = (float)u[1] - 1e10f * (1.0f - m.y);
  float v2 = (float)u[2] - 1e10f * (1.0f - m.z);
  float v3 = (float)u[3] - 1e10f * (1.0f - m.w);
  float mx = fmaxf(fmaxf(v0, v1), fmaxf(v2, v3));
  __shared__ float red[4];
  for (int off = 32; off > 0; off >>= 1) mx = fmaxf(mx, __shfl_xor(mx, off, 64));
  if ((t & 63) == 0) red[t >> 6] = mx;
  __syncthreads();
  mx = fmaxf(fmaxf(red[0], red[1]), fmaxf(red[2], red[3]));
  const float e0 = __expf(v0 - mx), e1 = __expf(v1 - mx);
  const float e2 = __expf(v2 - mx), e3 = __expf(v3 - mx);
  float sm = e0 + e1 + e2 + e3;
  __syncthreads();
  for (int off = 32; off > 0; off >>= 1) sm += __shfl_xor(sm, off, 64);
  if ((t & 63) == 0) red[t >> 6] = sm;
  __syncthreads();
  sm = red[0] + red[1] + red[2] + red[3];
  const float inv = 1.0f / sm;
  ushort4 o;
  o.x = f2bf(e0 * inv);
  o.y = f2bf(e1 * inv);
  o.z = f2bf(e2 * inv);
  o.w = f2bf(e3 * inv);
  ((ushort4*)(p + ((size_t)lb * NS + ri) * NS))[t] = o;
}

// ---------------- launcher ----------------
extern "C" void kernel_launch(void* const* d_in, const int* in_sizes, int n_in,
                              void* d_out, int out_size, void* d_ws,
                              size_t ws_size, hipStream_t stream) {
  const int* relation   = (const int*)d_in[0];
  const float* lhs      = (const float*)d_in[1];
  const int* sub_head   = (const int*)d_in[2];
  const int* sub_tail   = (const int*)d_in[3];
  const float* att_mask = (const float*)d_in[4];
  const float* rel_emb  = (const float*)d_in[5];
  const float* W_rf     = (const float*)d_in[6];
  const float* b_rf     = (const float*)d_in[7];
  const float* gamma    = (const float*)d_in[8];
  const float* beta     = (const float*)d_in[9];
  const float* W_wd     = (const float*)d_in[10];
  const float* W_bd     = (const float*)d_in[11];
  const float* Wq       = (const float*)d_in[12];
  const float* bq       = (const float*)d_in[13];
  const float* Wk       = (const float*)d_in[14];
  const float* bk       = (const float*)d_in[15];
  const float* Wv       = (const float*)d_in[16];
  const float* bv       = (const float*)d_in[17];
  const float* W_obj    = (const float*)d_in[18];
  const float* b_obj    = (const float*)d_in[19];

  char* ws = (char*)d_ws;
  // offsets (all 256B aligned)
  unsigned short* Wcat = (unsigned short*)(ws + 0);          //  3,538,944
  float* bcat  = (float*)(ws + 3538944);                     //      9,216
  float* wt    = (float*)(ws + 3548160);                     //     98,304
  float* bs    = (float*)(ws + 3646464);                     //     98,304
  float* reT   = (float*)(ws + 3744768);                     //     98,304
  float* condT = (float*)(ws + 3843072);                     //    196,608
  unsigned short* xbf = (unsigned short*)(ws + 4039680);     // 50,331,648
  unsigned short* qkv = (unsigned short*)(ws + 54371328);    // 100,663,296 (q|k compact)
  unsigned short* vT  = (unsigned short*)(ws + 155034624);   // 50,331,648
  char* attbuf = ws + 205366272;                             // CB*(2MB e + 2MB p)

  float* out_pred = (float*)d_out;
  float* out_hidden = out_pred + NBS;

  const size_t fixed = 205366272ull;
  size_t avail = ws_size > fixed ? ws_size - fixed : 0;
  int CB = 32;
  while (CB > 1 && (size_t)CB * ((size_t)NS * NS * 2 + (size_t)NS * NS * 2) > avail)
    CB >>= 1;
  _Float16* ebuf = (_Float16*)attbuf;                         // CB*2,097,152
  unsigned short* pbuf =
      (unsigned short*)(attbuf + (size_t)CB * NS * NS * 2);   // CB*2,097,152

  prep_w<<<dim3(NQKV), dim3(256), 0, stream>>>(Wq, bq, Wk, bk, Wv, bv, Wcat, bcat);
  cond_pre<<<dim3(NB), dim3(256), 0, stream>>>(relation, lhs, sub_head, sub_tail,
                                               rel_emb, reT, condT);
  cond_rf<<<dim3(NH / 8), dim3(256), 0, stream>>>(W_rf, b_rf, reT, condT);
  cond_wb<<<dim3(NH / 4), dim3(256), 0, stream>>>(W_wd, W_bd, gamma, beta, condT,
                                                  wt, bs);
  ln_kernel<<<dim3(NBS), dim3(64), 0, stream>>>(lhs, wt, bs, xbf);
  hipMemsetAsync(out_pred, 0, (size_t)NBS * sizeof(float), stream);

  // QKV: [32768,768] @ Wcat[2304,768]^T -> relu(+bias); q,k compact; v -> vT
  // via LDS-staged transpose (no separate transpose dispatch)
  gemm256<256, 1, 1, 1, 0, 1, 0>
      <<<dim3(NQKV / 256, NBS / 256, 1), dim3(512), 131072, stream>>>(
          xbf, 0, NH, Wcat, 0, NH, qkv, 0, NH, bcat, nullptr, 0, 0, NH, vT,
          nullptr, nullptr, nullptr);

  for (int b0 = 0; b0 < NB; b0 += 32) {
    // scores: e = q_c @ k_c^T  (f16 out)
    gemm256<256, 2, 0, 0, 0, 0, 0>
        <<<dim3(NS / 256, NS / 256, 32), dim3(512), 131072, stream>>>(
            qkv + (size_t)b0 * NS * NH, (long long)NS * NH, NH,
            qkv + (size_t)NBS * NH + (size_t)b0 * NS * NH, (long long)NS * NH, NH,
            ebuf, (long long)NS * NS, NS, nullptr, nullptr, 0, 0, NH, nullptr,
            nullptr, nullptr, nullptr);
    // softmax: f16 rows -> compact bf16 probs (f32 math inside)
    softmax_kernel<<<dim3(NS, 32), dim3(256), 0, stream>>>(ebuf, pbuf, att_mask,
                                                           b0);
    // hidden = probs @ v + x ; fused head projection (TM=128: 3 exact rounds)
    gemm256<128, 0, 0, 0, 1, 0, 1>
        <<<dim3(NH / 256, NS / 128, 32), dim3(512), 98304, stream>>>(
            pbuf, (long long)NS * NS, NS,
            vT + (size_t)b0 * NH * NS, (long long)NH * NS, NS,
            out_hidden + (size_t)b0 * NS * NH, (long long)NS * NH, NH, nullptr,
            xbf + (size_t)b0 * NS * NH, (long long)NS * NH, NH, NS, nullptr,
            W_obj, b_obj, out_pred + (size_t)b0 * NS);
  }
}